// Round 2
// baseline (285.527 us; speedup 1.0000x reference)
//
#include <hip/hip_runtime.h>
#include <hip/hip_bf16.h>

// MultiHeadSelfAttention  B=4 S=2048 H=16 Dh=64 Dm=1024 (fp32 in/out detected
// at runtime; intermediates bf16).
// Round 11:
//  - gemm_qkv reverted to R9 m97-structure (71us, 726 TF). R10's 256^2
//    8-phase port regressed (83us): at K=1024 the 8-phase ceiling is ~848 TF
//    (m248), and 384 tiles @ 1 block/CU = 1.5 rounds (x0.75) -> 636 TF < m97.
//  - attn_flash_mfma: single-buffer issue-early/wait-late pipeline (T14).
//    Replaced {syncthreads; stage 4 loads; syncthreads (vmcnt(0) drain)} with
//    raw s_barrier + counted vmcnt: stage K(kt+1) after QK reads complete
//    (lgkm0+barrier), stage V(kt+1) after PV reads complete; loop-top
//    vmcnt(2) waits K only (V stays in flight), pre-PV vmcnt(2) waits V
//    (K(kt+1) stays in flight). K latency hides under softmax+PV; V latency
//    under next QK. LDS unchanged (occupancy preserved). setprio(1) around
//    QK and PV MFMA clusters (T5, attn-positive per m191).
// Keeps: S^T orientation, XCD swizzle, max-free softmax, l = P@ones,
// vt written transposed by gemm_qkv, cast pipeline, workspace layout.

typedef __bf16 bf16x8 __attribute__((ext_vector_type(8)));
typedef __bf16 bf16x4 __attribute__((ext_vector_type(4)));
typedef float  f32x4  __attribute__((ext_vector_type(4)));

#define SEQ 2048
#define NH  16
#define HD  64
#define DM  1024
#define RS  72

static __device__ __forceinline__ void gload_lds16(const __hip_bfloat16* g,
                                                   __hip_bfloat16* l) {
    __builtin_amdgcn_global_load_lds(
        (const __attribute__((address_space(1))) void*)g,
        (__attribute__((address_space(3))) void*)l, 16, 0, 0);
}

// ---------------------------------------------------------------------------
__global__ void detect_dtype_kernel(const unsigned short* __restrict__ x,
                                    int* __restrict__ flag) {
    if (threadIdx.x == 0 && blockIdx.x == 0) {
        int cnt = 0;
        for (int i = 0; i < 256; i += 2) {
            unsigned e = (x[i] >> 7) & 0xFFu;
            cnt += (e >= 0x70u && e <= 0x82u) ? 1 : 0;
        }
        *flag = (cnt >= 64) ? 0 : 1;   // 0 = bf16 data, 1 = fp32 data
    }
}

// ---------------------------------------------------------------------------
__global__ __launch_bounds__(256) void cast4_kernel(
    const void* __restrict__ src, __hip_bfloat16* __restrict__ dst,
    const int* __restrict__ flag, int n4)
{
    const int i = blockIdx.x * 256 + threadIdx.x;
    if (i >= n4) return;
    bf16x4 o;
    if (*flag) {
        f32x4 f = ((const f32x4*)src)[i];
        #pragma unroll
        for (int j = 0; j < 4; ++j) o[j] = (__bf16)f[j];
    } else {
        o = ((const bf16x4*)src)[i];
    }
    ((bf16x4*)dst)[i] = o;
}

__global__ __launch_bounds__(256) void cast4x3_kernel(
    const void* s0, const void* s1, const void* s2,
    __hip_bfloat16* d0, __hip_bfloat16* d1, __hip_bfloat16* d2,
    const int* __restrict__ flag, int n4)
{
    const int i = blockIdx.x * 256 + threadIdx.x;
    if (i >= n4) return;
    const void* s = (blockIdx.y == 0) ? s0 : (blockIdx.y == 1) ? s1 : s2;
    __hip_bfloat16* d = (blockIdx.y == 0) ? d0 : (blockIdx.y == 1) ? d1 : d2;
    bf16x4 o;
    if (*flag) {
        f32x4 f = ((const f32x4*)s)[i];
        #pragma unroll
        for (int j = 0; j < 4; ++j) o[j] = (__bf16)f[j];
    } else {
        o = ((const bf16x4*)s)[i];
    }
    ((bf16x4*)d)[i] = o;
}

// ---------------------------------------------------------------------------
// m97-style GEMM core.
// ---------------------------------------------------------------------------
struct GemmCoord {
    int l15, g, wm, wn, r0, c0;
    int aRead, bRead;
};
static __device__ __forceinline__ GemmCoord gemm_coords() {
    GemmCoord c;
    const int tid = threadIdx.x;
    const int lane = tid & 63, wv = tid >> 6;
    c.l15 = lane & 15; c.g = lane >> 4;
    c.wm = wv >> 1;    c.wn = wv & 1;
    c.r0 = tid >> 2;   c.c0 = tid & 3;
    c.aRead = (c.wm * 64 + c.l15) * 32 + c.g * 8;
    c.bRead = (c.wn * 64 + c.l15) * 32 + c.g * 8;
    return c;
}

#define GEMM_BODY(Aptr, Bptr, m0v, n0v)                                        \
    __shared__ __hip_bfloat16 As[128 * 32];                                    \
    __shared__ __hip_bfloat16 Bs[128 * 32];                                    \
    const GemmCoord cc = gemm_coords();                                        \
    const int wv = threadIdx.x >> 6;                                           \
    const __hip_bfloat16* Ag0 = (Aptr) + (size_t)((m0v) + cc.r0) * DM + cc.c0 * 8;      \
    const __hip_bfloat16* Ag1 = (Aptr) + (size_t)((m0v) + cc.r0 + 64) * DM + cc.c0 * 8; \
    const __hip_bfloat16* Bg0 = (Bptr) + (size_t)((n0v) + cc.r0) * DM + cc.c0 * 8;      \
    const __hip_bfloat16* Bg1 = (Bptr) + (size_t)((n0v) + cc.r0 + 64) * DM + cc.c0 * 8; \
    __hip_bfloat16* AsD0 = As + 512 * wv;                                      \
    __hip_bfloat16* AsD1 = As + 2048 + 512 * wv;                               \
    __hip_bfloat16* BsD0 = Bs + 512 * wv;                                      \
    __hip_bfloat16* BsD1 = Bs + 2048 + 512 * wv;                               \
    f32x4 acc[4][4];                                                           \
    _Pragma("unroll") for (int i = 0; i < 4; ++i)                              \
        _Pragma("unroll") for (int j = 0; j < 4; ++j)                          \
            acc[i][j] = (f32x4){0.f, 0.f, 0.f, 0.f};                           \
    for (int kb = 0; kb < DM; kb += 32) {                                      \
        __syncthreads();                                                       \
        gload_lds16(Ag0 + kb, AsD0);                                           \
        gload_lds16(Ag1 + kb, AsD1);                                           \
        gload_lds16(Bg0 + kb, BsD0);                                           \
        gload_lds16(Bg1 + kb, BsD1);                                           \
        __syncthreads();                                                       \
        bf16x8 af[4], bfr[4];                                                  \
        _Pragma("unroll") for (int i = 0; i < 4; ++i)                          \
            af[i] = *reinterpret_cast<const bf16x8*>(&As[cc.aRead + i * 512]); \
        _Pragma("unroll") for (int j = 0; j < 4; ++j)                          \
            bfr[j] = *reinterpret_cast<const bf16x8*>(&Bs[cc.bRead + j * 512]);\
        _Pragma("unroll") for (int i = 0; i < 4; ++i)                          \
            _Pragma("unroll") for (int j = 0; j < 4; ++j)                      \
                acc[i][j] = __builtin_amdgcn_mfma_f32_16x16x32_bf16(           \
                    af[i], bfr[j], acc[i][j], 0, 0, 0);                        \
    }

// Fused QKV (R9). widx 0/1 -> q/kk normal layout; widx 2 -> V stored
// transposed into vt[(b*16+h)*64+d][t] via 16x 8B stores.
__global__ __launch_bounds__(256) void gemm_qkv(
    const __hip_bfloat16* __restrict__ A,
    const __hip_bfloat16* __restrict__ Wb,
    const void* bq, const void* bk, const void* bv,
    __hip_bfloat16* q, __hip_bfloat16* kk, __hip_bfloat16* vt,
    const int* __restrict__ dflag)
{
    const int widx = blockIdx.y >> 3;
    const int m0 = blockIdx.x * 128;
    const int n0 = (blockIdx.y & 7) * 128;
    const __hip_bfloat16* B = Wb + (size_t)widx * DM * DM;
    const void* bias = (widx == 0) ? bq : (widx == 1) ? bk : bv;
    const bool f32 = (*dflag != 0);

    GEMM_BODY(A, B, m0, n0)

    if (widx == 2) {
        #pragma unroll
        for (int j = 0; j < 4; ++j) {
            const int col = n0 + cc.wn * 64 + j * 16 + cc.l15;
            const float bvv = f32 ? ((const float*)bias)[col]
                                  : __bfloat162float(((const __hip_bfloat16*)bias)[col]);
            #pragma unroll
            for (int i = 0; i < 4; ++i) {
                const int row0 = m0 + cc.wm * 64 + i * 16 + cc.g * 4; // r=0 row
                const int bb = row0 >> 11;
                const int t  = row0 & 2047;
                bf16x4 pv;
                #pragma unroll
                for (int r = 0; r < 4; ++r)
                    pv[r] = (__bf16)(acc[i][j][r] + bvv);
                *reinterpret_cast<bf16x4*>(
                    vt + (size_t)(bb * 1024 + col) * SEQ + t) = pv;
            }
        }
    } else {
        __hip_bfloat16* out = (widx == 0) ? q : kk;
        #pragma unroll
        for (int j = 0; j < 4; ++j) {
            const int col = n0 + cc.wn * 64 + j * 16 + cc.l15;
            const float bvv = f32 ? ((const float*)bias)[col]
                                  : __bfloat162float(((const __hip_bfloat16*)bias)[col]);
            #pragma unroll
            for (int i = 0; i < 4; ++i) {
                #pragma unroll
                for (int r = 0; r < 4; ++r) {
                    const int row = m0 + cc.wm * 64 + i * 16 + cc.g * 4 + r;
                    out[(size_t)row * DM + col] = __float2bfloat16(acc[i][j][r] + bvv);
                }
            }
        }
    }
}

__global__ __launch_bounds__(256) void gemm_out(
    const __hip_bfloat16* __restrict__ A,
    const __hip_bfloat16* __restrict__ B,
    const void* bias, void* __restrict__ outv,
    const int* __restrict__ dflag)
{
    const int m0 = blockIdx.x * 128;
    const int n0 = blockIdx.y * 128;
    const bool f32 = (*dflag != 0);

    GEMM_BODY(A, B, m0, n0)

    #pragma unroll
    for (int j = 0; j < 4; ++j) {
        const int col = n0 + cc.wn * 64 + j * 16 + cc.l15;
        const float bvv = f32 ? ((const float*)bias)[col]
                              : __bfloat162float(((const __hip_bfloat16*)bias)[col]);
        #pragma unroll
        for (int i = 0; i < 4; ++i) {
            #pragma unroll
            for (int r = 0; r < 4; ++r) {
                const int row = m0 + cc.wm * 64 + i * 16 + cc.g * 4 + r;
                const float val = acc[i][j][r] + bvv;
                if (f32) ((float*)outv)[(size_t)row * DM + col] = val;
                else ((__hip_bfloat16*)outv)[(size_t)row * DM + col] = __float2bfloat16(val);
            }
        }
    }
}

// ---------------------------------------------------------------------------
// Flash attention (S^T orientation) with issue-early/wait-late staging.
// Single-buffer K/V tiles; overwrite safety by {lgkmcnt(0); s_barrier; stage}
// after the last LDS read of the buffer; landing safety by per-wave counted
// vmcnt + s_barrier (each wave stages and waits its own chunks; barrier
// publishes). FIFO vmcnt order per iteration: K(kt+1) issued before V(kt+1).
// Loop-top vmcnt(2): drains K(kt) (+ any older stores/q-loads), leaves V(kt)
// in flight. Pre-PV vmcnt(2): drains V(kt), leaves K(kt+1) in flight.
// All stage branches are block-uniform (kt < qt).
// ---------------------------------------------------------------------------
__global__ __launch_bounds__(256) void attn_flash_mfma(
    const __hip_bfloat16* __restrict__ q,
    const __hip_bfloat16* __restrict__ k,
    const __hip_bfloat16* __restrict__ vt,   // [b][h][d][t]
    __hip_bfloat16* __restrict__ ctx)
{
    __shared__ __hip_bfloat16 Ks[64 * HD];        // 8KB swizzled K tile
    __shared__ __hip_bfloat16 Vs[HD * 64];        // 8KB swizzled VT tile
    __shared__ __hip_bfloat16 P[4][16 * RS];      // per-wave P (9.2KB)

    const int tid  = threadIdx.x;
    const int lane = tid & 63;
    const int wave = tid >> 6;
    const int g    = lane >> 4;
    const int l15  = lane & 15;
    const int l7   = l15 & 7;

    const int lid  = blockIdx.x;
    const int xcd  = lid & 7;
    const int slot = lid >> 3;
    const int p    = (slot >> 4) * 8 + xcd;   // 0..63 = b*16+h
    const int qp   = slot & 15;
    const int b    = p >> 4;
    const int h    = p & 15;

    const size_t hb = (size_t)b * SEQ * DM + (size_t)h * HD;
    const __hip_bfloat16* vth = vt + (size_t)(b * NH + h) * HD * SEQ;
    __hip_bfloat16* Pw = P[wave];

    const int c0  = wave * 64 + lane;
    const int c1  = 256 + wave * 64 + lane;
    const int kr0 = c0 >> 3, ks0 = ((c0 & 7) ^ (kr0 & 7)) * 8;
    const int kr1 = c1 >> 3, ks1 = ((c1 & 7) ^ (kr1 & 7)) * 8;
    __hip_bfloat16* KsD0 = Ks + wave * 512;
    __hip_bfloat16* KsD1 = Ks + 2048 + wave * 512;
    __hip_bfloat16* VsD0 = Vs + wave * 512;
    __hip_bfloat16* VsD1 = Vs + 2048 + wave * 512;

    const int f0off = ((g ^ l7)) * 8;
    const int f1off = (((4 + g) ^ l7)) * 8;

    bf16x8 ones;
    #pragma unroll
    for (int j = 0; j < 8; ++j) ones[j] = (__bf16)1.0f;

    #pragma unroll
    for (int half = 0; half < 2; ++half) {
        const int qt = half ? (SEQ / 64 - 1 - qp) : qp;
        const int q0 = qt * 64;

        const int qrow = q0 + wave * 16 + l15;
        const __hip_bfloat16* qp_ = q + hb + (size_t)qrow * DM + g * 8;
        bf16x8 qf0 = *reinterpret_cast<const bf16x8*>(qp_);
        bf16x8 qf1 = *reinterpret_cast<const bf16x8*>(qp_ + 32);
        #pragma unroll
        for (int j = 0; j < 8; ++j) {
            qf0[j] = (__bf16)((float)qf0[j] * 0.125f);   // 1/sqrt(64)
            qf1[j] = (__bf16)((float)qf1[j] * 0.125f);
        }

        f32x4 o[4];
        #pragma unroll
        for (int j = 0; j < 4; ++j) o[j] = (f32x4){0.f, 0.f, 0.f, 0.f};
        f32x4 zl = (f32x4){0.f, 0.f, 0.f, 0.f};   // row sums of P

        // ---- prologue: stage tile 0 (K then V; FIFO order matters) ------
        gload_lds16(k + hb + (size_t)kr0 * DM + ks0, KsD0);
        gload_lds16(k + hb + (size_t)kr1 * DM + ks1, KsD1);
        gload_lds16(vth + (size_t)kr0 * SEQ + ks0, VsD0);
        gload_lds16(vth + (size_t)kr1 * SEQ + ks1, VsD1);

        for (int kt = 0; kt <= qt; ++kt) {
            const int nbase = (kt + 1) * 64;   // next tile base

            // ---- K(kt) landed (V(kt) may still fly) ---------------------
            asm volatile("s_waitcnt vmcnt(2)" ::: "memory");
            __builtin_amdgcn_s_barrier();

            // ---- S^T = K (Q/8)^T ---------------------------------------
            f32x4 s[4];
            __builtin_amdgcn_s_setprio(1);
            #pragma unroll
            for (int j = 0; j < 4; ++j) {
                const int krow = (j * 16 + l15) * 64;
                bf16x8 kf0 = *reinterpret_cast<const bf16x8*>(&Ks[krow + f0off]);
                bf16x8 kf1 = *reinterpret_cast<const bf16x8*>(&Ks[krow + f1off]);
                f32x4 z = (f32x4){0.f, 0.f, 0.f, 0.f};
                z = __builtin_amdgcn_mfma_f32_16x16x32_bf16(kf0, qf0, z, 0, 0, 0);
                z = __builtin_amdgcn_mfma_f32_16x16x32_bf16(kf1, qf1, z, 0, 0, 0);
                s[j] = z;   // s[j][r]: key = j*16 + g*4 + r, query = l15
            }
            __builtin_amdgcn_s_setprio(0);

            // ---- all waves done reading Ks -> stage K(kt+1) -------------
            asm volatile("s_waitcnt lgkmcnt(0)" ::: "memory");
            __builtin_amdgcn_s_barrier();
            if (kt < qt) {
                gload_lds16(k + hb + (size_t)(nbase + kr0) * DM + ks0, KsD0);
                gload_lds16(k + hb + (size_t)(nbase + kr1) * DM + ks1, KsD1);
            }

            // ---- causal mask (diagonal tile only) -----------------------
            if (kt == qt) {
                const int qq = wave * 16 + l15;
                #pragma unroll
                for (int j = 0; j < 4; ++j) {
                    #pragma unroll
                    for (int r = 0; r < 4; ++r) {
                        const int key = j * 16 + g * 4 + r;
                        if (key > qq) s[j][r] = -1e30f;
                    }
                }
            }

            // ---- max-free softmax: p = exp(s) ---------------------------
            #pragma unroll
            for (int j = 0; j < 4; ++j)
                #pragma unroll
                for (int r = 0; r < 4; ++r)
                    s[j][r] = __expf(s[j][r]);

            // ---- P: S^T C-layout -> A-layout, one b64 per j -------------
            #pragma unroll
            for (int j = 0; j < 4; ++j) {
                bf16x4 pv;
                #pragma unroll
                for (int r = 0; r < 4; ++r) pv[r] = (__bf16)s[j][r];
                *reinterpret_cast<bf16x4*>(&Pw[l15 * RS + j * 16 + g * 4]) = pv;
            }

            const bf16x8 a0 = *reinterpret_cast<const bf16x8*>(&Pw[l15 * RS + g * 8]);
            const bf16x8 a1 = *reinterpret_cast<const bf16x8*>(&Pw[l15 * RS + 32 + g * 8]);

            // ---- l += P @ ones ------------------------------------------
            zl = __builtin_amdgcn_mfma_f32_16x16x32_bf16(a0, ones, zl, 0, 0, 0);
            zl = __builtin_amdgcn_mfma_f32_16x16x32_bf16(a1, ones, zl, 0, 0, 0);

            // ---- V(kt) landed (K(kt+1) may still fly) -------------------
            if (kt < qt) asm volatile("s_waitcnt vmcnt(2)" ::: "memory");
            else         asm volatile("s_waitcnt vmcnt(0)" ::: "memory");
            __builtin_amdgcn_s_barrier();

            // ---- O += P V  (VT frags from LDS) --------------------------
            __builtin_amdgcn_s_setprio(1);
            #pragma unroll
            for (int jd = 0; jd < 4; ++jd) {
                const int vrow = (jd * 16 + l15) * 64;
                const bf16x8 b0 = *reinterpret_cast<const bf16x8*>(&Vs[vrow + f0off]);
                const bf16x8 b1 = *reinterpret_cast<const bf16x8*>(&Vs[vrow + f1off]);
                o[jd] = __builtin_amdgcn_mfma_f32_16x16x32_bf16(a0, b0, o[jd], 0, 0, 0);
                o[jd] = __builtin_amdgcn_mfma_f32_16x16x32_bf16(a1, b1, o[jd], 0, 0, 0);
            }
            __builtin_amdgcn_s_setprio(0);

            // ---- all waves done reading Vs -> stage V(kt+1) -------------
            asm volatile("s_waitcnt lgkmcnt(0)" ::: "memory");
            __builtin_amdgcn_s_barrier();
            if (kt < qt) {
                gload_lds16(vth + (size_t)kr0 * SEQ + nbase + ks0, VsD0);
                gload_lds16(vth + (size_t)kr1 * SEQ + nbase + ks1, VsD1);
            }
        }

        // ---- epilogue: ctx = O / l --------------------------------------
        #pragma unroll
        for (int r = 0; r < 4; ++r) {
            const float inv = 1.f / zl[r];
            const int sq = q0 + wave * 16 + g * 4 + r;
            #pragma unroll
            for (int jd = 0; jd < 4; ++jd)
                ctx[hb + (size_t)sq * DM + jd * 16 + l15] =
                    __float2bfloat16(o[jd][r] * inv);
        }
    }
}

// ---------------------------------------------------------------------------
extern "C" void kernel_launch(void* const* d_in, const int* in_sizes, int n_in,
                              void* d_out, int out_size, void* d_ws, size_t ws_size,
                              hipStream_t stream) {
    const int M = 4 * SEQ;   // 8192

    // size-based input mapping
    int xi = 0, wi[4] = {-1, -1, -1, -1}, bi[4] = {-1, -1, -1, -1};
    int nw = 0, nb = 0;
    for (int i = 0; i < n_in; ++i) {
        if (in_sizes[i] == 4 * SEQ * DM) xi = i;
        else if (in_sizes[i] == DM * DM && nw < 4) wi[nw++] = i;
        else if (in_sizes[i] == DM && nb < 4) bi[nb++] = i;
    }
    if (nw < 4 || nb < 4) {
        const int wOff = n_in - 8;
        for (int j = 0; j < 4; ++j) { wi[j] = wOff + 2 * j; bi[j] = wOff + 2 * j + 1; }
    }
    const void* x  = d_in[xi];
    const void* W[4]  = {d_in[wi[0]], d_in[wi[1]], d_in[wi[2]], d_in[wi[3]]};
    const void* Bs[4] = {d_in[bi[0]], d_in[bi[1]], d_in[bi[2]], d_in[bi[3]]};

    // ws: q | kk | vt | flag (50.33 MB + 4). ctx aliases q. vt (V transposed,
    // written directly by gemm_qkv) occupies the old vv slot.
    const size_t mat = (size_t)M * DM;
    __hip_bfloat16* q   = (__hip_bfloat16*)d_ws;
    __hip_bfloat16* kk  = q + mat;
    __hip_bfloat16* vt  = kk + mat;
    __hip_bfloat16* ctx = q;
    int* flag = (int*)((char*)d_ws + 3 * mat * sizeof(__hip_bfloat16));

    // d_out scratch: xb (16.78 MB) + wb (6.29 MB); both dead before gemm_out.
    __hip_bfloat16* xb  = (__hip_bfloat16*)d_out;
    __hip_bfloat16* wb  = xb + mat;
    __hip_bfloat16* wob = kk;                       // Wo bf16, after attention

    detect_dtype_kernel<<<1, 64, 0, stream>>>((const unsigned short*)x, flag);

    cast4_kernel<<<dim3((int)(mat / 4 / 256)), 256, 0, stream>>>(x, xb, flag, (int)(mat / 4));
    cast4x3_kernel<<<dim3(DM * DM / 4 / 256, 3), 256, 0, stream>>>(
        W[0], W[1], W[2], wb, wb + (size_t)DM * DM, wb + 2 * (size_t)DM * DM,
        flag, DM * DM / 4);

    gemm_qkv<<<dim3(M / 128, 24), 256, 0, stream>>>(
        xb, wb, Bs[0], Bs[1], Bs[2], q, kk, vt, flag);

    attn_flash_mfma<<<dim3(1024), 256, 0, stream>>>(q, kk, vt, ctx);

    cast4_kernel<<<dim3(DM * DM / 4 / 256), 256, 0, stream>>>(W[3], wob, flag, DM * DM / 4);

    gemm_out<<<dim3(M / 128, DM / 128), 256, 0, stream>>>(ctx, wob, Bs[3], d_out, flag);
}

// Round 3
// 267.765 us; speedup vs baseline: 1.0663x; 1.0663x over previous
//
#include <hip/hip_runtime.h>
#include <hip/hip_bf16.h>

// MultiHeadSelfAttention  B=4 S=2048 H=16 Dh=64 Dm=1024 (fp32 in/out detected
// at runtime; intermediates bf16).
// Round 12:
//  - attn_flash_mfma reverted to R9 exact (R11's counted-vmcnt pipeline
//    regressed 70.6->82.8us: K/V are L2-resident so stage latency was never
//    on the critical path; extra barriers+lgkm drains cost inter-wave drift).
//  - detect_dtype + cast4(x) + cast4x3(W0-2) merged into ONE prep_cast
//    kernel (7 -> 5 launches). Wall arithmetic across R0-R2 shows
//    wall = sum(dispatches) + ~90us => ~10-13us per launch overhead.
//    Each prep block re-derives the dtype flag locally from x[0..255]
//    (ballot+popc over the same 128 samples); block 0 writes *flag for
//    gemm_qkv/gemm_out bias/output branches. W3 cast stays separate (dest
//    aliases kk, free only after attn).
// Keeps: R9 gemm_qkv (m97 structure, V stored transposed), S^T attn,
// XCD swizzle, max-free softmax, l = P@ones, workspace layout.

typedef __bf16 bf16x8 __attribute__((ext_vector_type(8)));
typedef __bf16 bf16x4 __attribute__((ext_vector_type(4)));
typedef float  f32x4  __attribute__((ext_vector_type(4)));

#define SEQ 2048
#define NH  16
#define HD  64
#define DM  1024
#define RS  72

static __device__ __forceinline__ void gload_lds16(const __hip_bfloat16* g,
                                                   __hip_bfloat16* l) {
    __builtin_amdgcn_global_load_lds(
        (const __attribute__((address_space(1))) void*)g,
        (__attribute__((address_space(3))) void*)l, 16, 0, 0);
}

// ---------------------------------------------------------------------------
// prep_cast: fused dtype-detect + x->xb + W0..2->wb casts.
// grid: [0,8192) -> x quads; [8192, 8192+3*1024) -> W segments.
// Every block derives the flag locally (2 cached shorts/lane + ballot).
// ---------------------------------------------------------------------------
__global__ __launch_bounds__(256) void prep_cast(
    const void* __restrict__ x,
    const void* __restrict__ w0, const void* __restrict__ w1,
    const void* __restrict__ w2,
    __hip_bfloat16* __restrict__ xb, __hip_bfloat16* __restrict__ wb,
    int* __restrict__ flag)
{
    // local dtype detection: same 128 samples (x[0],x[2],...,x[254]) as the
    // old detect kernel. lane l checks shorts 4l and 4l+2.
    const unsigned short* xs = (const unsigned short*)x;
    const int lane = threadIdx.x & 63;
    const unsigned e0 = (xs[lane * 4]     >> 7) & 0xFFu;
    const unsigned e1 = (xs[lane * 4 + 2] >> 7) & 0xFFu;
    const unsigned long long b0 = __ballot(e0 >= 0x70u && e0 <= 0x82u);
    const unsigned long long b1 = __ballot(e1 >= 0x70u && e1 <= 0x82u);
    const int cnt = __popcll(b0) + __popcll(b1);
    const bool f32 = (cnt < 64);           // 1 = fp32 data

    const int gid = blockIdx.x;
    if (gid == 0 && threadIdx.x == 0) *flag = f32 ? 1 : 0;

    const void* src;
    __hip_bfloat16* dst;
    int i;
    if (gid < 8192) {
        src = x; dst = xb;
        i = gid * 256 + threadIdx.x;
    } else {
        const int idx = gid - 8192;
        const int w   = idx >> 10;         // 0..2
        const int lb  = idx & 1023;
        src = (w == 0) ? w0 : (w == 1) ? w1 : w2;
        dst = wb + (size_t)w * DM * DM;
        i = lb * 256 + threadIdx.x;
    }

    bf16x4 o;
    if (f32) {
        f32x4 f = ((const f32x4*)src)[i];
        #pragma unroll
        for (int j = 0; j < 4; ++j) o[j] = (__bf16)f[j];
    } else {
        o = ((const bf16x4*)src)[i];
    }
    ((bf16x4*)dst)[i] = o;
}

// cast4 kept for the late Wo cast (dest aliases kk, free only after attn).
__global__ __launch_bounds__(256) void cast4_kernel(
    const void* __restrict__ src, __hip_bfloat16* __restrict__ dst,
    const int* __restrict__ flag, int n4)
{
    const int i = blockIdx.x * 256 + threadIdx.x;
    if (i >= n4) return;
    bf16x4 o;
    if (*flag) {
        f32x4 f = ((const f32x4*)src)[i];
        #pragma unroll
        for (int j = 0; j < 4; ++j) o[j] = (__bf16)f[j];
    } else {
        o = ((const bf16x4*)src)[i];
    }
    ((bf16x4*)dst)[i] = o;
}

// ---------------------------------------------------------------------------
// m97-style GEMM core.
// ---------------------------------------------------------------------------
struct GemmCoord {
    int l15, g, wm, wn, r0, c0;
    int aRead, bRead;
};
static __device__ __forceinline__ GemmCoord gemm_coords() {
    GemmCoord c;
    const int tid = threadIdx.x;
    const int lane = tid & 63, wv = tid >> 6;
    c.l15 = lane & 15; c.g = lane >> 4;
    c.wm = wv >> 1;    c.wn = wv & 1;
    c.r0 = tid >> 2;   c.c0 = tid & 3;
    c.aRead = (c.wm * 64 + c.l15) * 32 + c.g * 8;
    c.bRead = (c.wn * 64 + c.l15) * 32 + c.g * 8;
    return c;
}

#define GEMM_BODY(Aptr, Bptr, m0v, n0v)                                        \
    __shared__ __hip_bfloat16 As[128 * 32];                                    \
    __shared__ __hip_bfloat16 Bs[128 * 32];                                    \
    const GemmCoord cc = gemm_coords();                                        \
    const int wv = threadIdx.x >> 6;                                           \
    const __hip_bfloat16* Ag0 = (Aptr) + (size_t)((m0v) + cc.r0) * DM + cc.c0 * 8;      \
    const __hip_bfloat16* Ag1 = (Aptr) + (size_t)((m0v) + cc.r0 + 64) * DM + cc.c0 * 8; \
    const __hip_bfloat16* Bg0 = (Bptr) + (size_t)((n0v) + cc.r0) * DM + cc.c0 * 8;      \
    const __hip_bfloat16* Bg1 = (Bptr) + (size_t)((n0v) + cc.r0 + 64) * DM + cc.c0 * 8; \
    __hip_bfloat16* AsD0 = As + 512 * wv;                                      \
    __hip_bfloat16* AsD1 = As + 2048 + 512 * wv;                               \
    __hip_bfloat16* BsD0 = Bs + 512 * wv;                                      \
    __hip_bfloat16* BsD1 = Bs + 2048 + 512 * wv;                               \
    f32x4 acc[4][4];                                                           \
    _Pragma("unroll") for (int i = 0; i < 4; ++i)                              \
        _Pragma("unroll") for (int j = 0; j < 4; ++j)                          \
            acc[i][j] = (f32x4){0.f, 0.f, 0.f, 0.f};                           \
    for (int kb = 0; kb < DM; kb += 32) {                                      \
        __syncthreads();                                                       \
        gload_lds16(Ag0 + kb, AsD0);                                           \
        gload_lds16(Ag1 + kb, AsD1);                                           \
        gload_lds16(Bg0 + kb, BsD0);                                           \
        gload_lds16(Bg1 + kb, BsD1);                                           \
        __syncthreads();                                                       \
        bf16x8 af[4], bfr[4];                                                  \
        _Pragma("unroll") for (int i = 0; i < 4; ++i)                          \
            af[i] = *reinterpret_cast<const bf16x8*>(&As[cc.aRead + i * 512]); \
        _Pragma("unroll") for (int j = 0; j < 4; ++j)                          \
            bfr[j] = *reinterpret_cast<const bf16x8*>(&Bs[cc.bRead + j * 512]);\
        _Pragma("unroll") for (int i = 0; i < 4; ++i)                          \
            _Pragma("unroll") for (int j = 0; j < 4; ++j)                      \
                acc[i][j] = __builtin_amdgcn_mfma_f32_16x16x32_bf16(           \
                    af[i], bfr[j], acc[i][j], 0, 0, 0);                        \
    }

// Fused QKV (R9). widx 0/1 -> q/kk normal layout; widx 2 -> V stored
// transposed into vt[(b*16+h)*64+d][t] via 16x 8B stores.
__global__ __launch_bounds__(256) void gemm_qkv(
    const __hip_bfloat16* __restrict__ A,
    const __hip_bfloat16* __restrict__ Wb,
    const void* bq, const void* bk, const void* bv,
    __hip_bfloat16* q, __hip_bfloat16* kk, __hip_bfloat16* vt,
    const int* __restrict__ dflag)
{
    const int widx = blockIdx.y >> 3;
    const int m0 = blockIdx.x * 128;
    const int n0 = (blockIdx.y & 7) * 128;
    const __hip_bfloat16* B = Wb + (size_t)widx * DM * DM;
    const void* bias = (widx == 0) ? bq : (widx == 1) ? bk : bv;
    const bool f32 = (*dflag != 0);

    GEMM_BODY(A, B, m0, n0)

    if (widx == 2) {
        #pragma unroll
        for (int j = 0; j < 4; ++j) {
            const int col = n0 + cc.wn * 64 + j * 16 + cc.l15;
            const float bvv = f32 ? ((const float*)bias)[col]
                                  : __bfloat162float(((const __hip_bfloat16*)bias)[col]);
            #pragma unroll
            for (int i = 0; i < 4; ++i) {
                const int row0 = m0 + cc.wm * 64 + i * 16 + cc.g * 4; // r=0 row
                const int bb = row0 >> 11;
                const int t  = row0 & 2047;
                bf16x4 pv;
                #pragma unroll
                for (int r = 0; r < 4; ++r)
                    pv[r] = (__bf16)(acc[i][j][r] + bvv);
                *reinterpret_cast<bf16x4*>(
                    vt + (size_t)(bb * 1024 + col) * SEQ + t) = pv;
            }
        }
    } else {
        __hip_bfloat16* out = (widx == 0) ? q : kk;
        #pragma unroll
        for (int j = 0; j < 4; ++j) {
            const int col = n0 + cc.wn * 64 + j * 16 + cc.l15;
            const float bvv = f32 ? ((const float*)bias)[col]
                                  : __bfloat162float(((const __hip_bfloat16*)bias)[col]);
            #pragma unroll
            for (int i = 0; i < 4; ++i) {
                #pragma unroll
                for (int r = 0; r < 4; ++r) {
                    const int row = m0 + cc.wm * 64 + i * 16 + cc.g * 4 + r;
                    out[(size_t)row * DM + col] = __float2bfloat16(acc[i][j][r] + bvv);
                }
            }
        }
    }
}

__global__ __launch_bounds__(256) void gemm_out(
    const __hip_bfloat16* __restrict__ A,
    const __hip_bfloat16* __restrict__ B,
    const void* bias, void* __restrict__ outv,
    const int* __restrict__ dflag)
{
    const int m0 = blockIdx.x * 128;
    const int n0 = blockIdx.y * 128;
    const bool f32 = (*dflag != 0);

    GEMM_BODY(A, B, m0, n0)

    #pragma unroll
    for (int j = 0; j < 4; ++j) {
        const int col = n0 + cc.wn * 64 + j * 16 + cc.l15;
        const float bvv = f32 ? ((const float*)bias)[col]
                              : __bfloat162float(((const __hip_bfloat16*)bias)[col]);
        #pragma unroll
        for (int i = 0; i < 4; ++i) {
            #pragma unroll
            for (int r = 0; r < 4; ++r) {
                const int row = m0 + cc.wm * 64 + i * 16 + cc.g * 4 + r;
                const float val = acc[i][j][r] + bvv;
                if (f32) ((float*)outv)[(size_t)row * DM + col] = val;
                else ((__hip_bfloat16*)outv)[(size_t)row * DM + col] = __float2bfloat16(val);
            }
        }
    }
}

// ---------------------------------------------------------------------------
// Flash attention (S^T orientation) — R9 exact.
// ---------------------------------------------------------------------------
__global__ __launch_bounds__(256) void attn_flash_mfma(
    const __hip_bfloat16* __restrict__ q,
    const __hip_bfloat16* __restrict__ k,
    const __hip_bfloat16* __restrict__ vt,   // [b][h][d][t]
    __hip_bfloat16* __restrict__ ctx)
{
    __shared__ __hip_bfloat16 Ks[64 * HD];        // 8KB swizzled K tile
    __shared__ __hip_bfloat16 Vs[HD * 64];        // 8KB swizzled VT tile
    __shared__ __hip_bfloat16 P[4][16 * RS];      // per-wave P (9.2KB)

    const int tid  = threadIdx.x;
    const int lane = tid & 63;
    const int wave = tid >> 6;
    const int g    = lane >> 4;
    const int l15  = lane & 15;
    const int l7   = l15 & 7;

    const int lid  = blockIdx.x;
    const int xcd  = lid & 7;
    const int slot = lid >> 3;
    const int p    = (slot >> 4) * 8 + xcd;   // 0..63 = b*16+h
    const int qp   = slot & 15;
    const int b    = p >> 4;
    const int h    = p & 15;

    const size_t hb = (size_t)b * SEQ * DM + (size_t)h * HD;
    const __hip_bfloat16* vth = vt + (size_t)(b * NH + h) * HD * SEQ;
    __hip_bfloat16* Pw = P[wave];

    const int c0  = wave * 64 + lane;
    const int c1  = 256 + wave * 64 + lane;
    const int kr0 = c0 >> 3, ks0 = ((c0 & 7) ^ (kr0 & 7)) * 8;
    const int kr1 = c1 >> 3, ks1 = ((c1 & 7) ^ (kr1 & 7)) * 8;
    __hip_bfloat16* KsD0 = Ks + wave * 512;
    __hip_bfloat16* KsD1 = Ks + 2048 + wave * 512;
    __hip_bfloat16* VsD0 = Vs + wave * 512;
    __hip_bfloat16* VsD1 = Vs + 2048 + wave * 512;

    const int f0off = ((g ^ l7)) * 8;
    const int f1off = (((4 + g) ^ l7)) * 8;

    bf16x8 ones;
    #pragma unroll
    for (int j = 0; j < 8; ++j) ones[j] = (__bf16)1.0f;

    #pragma unroll
    for (int half = 0; half < 2; ++half) {
        const int qt = half ? (SEQ / 64 - 1 - qp) : qp;
        const int q0 = qt * 64;

        const int qrow = q0 + wave * 16 + l15;
        const __hip_bfloat16* qp_ = q + hb + (size_t)qrow * DM + g * 8;
        bf16x8 qf0 = *reinterpret_cast<const bf16x8*>(qp_);
        bf16x8 qf1 = *reinterpret_cast<const bf16x8*>(qp_ + 32);
        #pragma unroll
        for (int j = 0; j < 8; ++j) {
            qf0[j] = (__bf16)((float)qf0[j] * 0.125f);   // 1/sqrt(64)
            qf1[j] = (__bf16)((float)qf1[j] * 0.125f);
        }

        f32x4 o[4];
        #pragma unroll
        for (int j = 0; j < 4; ++j) o[j] = (f32x4){0.f, 0.f, 0.f, 0.f};
        f32x4 zl = (f32x4){0.f, 0.f, 0.f, 0.f};   // row sums of P

        for (int kt = 0; kt <= qt; ++kt) {
            const int kbase = kt * 64;

            __syncthreads();
            gload_lds16(k + hb + (size_t)(kbase + kr0) * DM + ks0, KsD0);
            gload_lds16(k + hb + (size_t)(kbase + kr1) * DM + ks1, KsD1);
            gload_lds16(vth + (size_t)kr0 * SEQ + kbase + ks0, VsD0);
            gload_lds16(vth + (size_t)kr1 * SEQ + kbase + ks1, VsD1);
            __syncthreads();

            f32x4 s[4];
            #pragma unroll
            for (int j = 0; j < 4; ++j) {
                const int krow = (j * 16 + l15) * 64;
                bf16x8 kf0 = *reinterpret_cast<const bf16x8*>(&Ks[krow + f0off]);
                bf16x8 kf1 = *reinterpret_cast<const bf16x8*>(&Ks[krow + f1off]);
                f32x4 z = (f32x4){0.f, 0.f, 0.f, 0.f};
                z = __builtin_amdgcn_mfma_f32_16x16x32_bf16(kf0, qf0, z, 0, 0, 0);
                z = __builtin_amdgcn_mfma_f32_16x16x32_bf16(kf1, qf1, z, 0, 0, 0);
                s[j] = z;   // s[j][r]: key = j*16 + g*4 + r, query = l15
            }

            if (kt == qt) {
                const int qq = wave * 16 + l15;
                #pragma unroll
                for (int j = 0; j < 4; ++j) {
                    #pragma unroll
                    for (int r = 0; r < 4; ++r) {
                        const int key = j * 16 + g * 4 + r;
                        if (key > qq) s[j][r] = -1e30f;
                    }
                }
            }

            #pragma unroll
            for (int j = 0; j < 4; ++j)
                #pragma unroll
                for (int r = 0; r < 4; ++r)
                    s[j][r] = __expf(s[j][r]);

            #pragma unroll
            for (int j = 0; j < 4; ++j) {
                bf16x4 pv;
                #pragma unroll
                for (int r = 0; r < 4; ++r) pv[r] = (__bf16)s[j][r];
                *reinterpret_cast<bf16x4*>(&Pw[l15 * RS + j * 16 + g * 4]) = pv;
            }

            const bf16x8 a0 = *reinterpret_cast<const bf16x8*>(&Pw[l15 * RS + g * 8]);
            const bf16x8 a1 = *reinterpret_cast<const bf16x8*>(&Pw[l15 * RS + 32 + g * 8]);

            zl = __builtin_amdgcn_mfma_f32_16x16x32_bf16(a0, ones, zl, 0, 0, 0);
            zl = __builtin_amdgcn_mfma_f32_16x16x32_bf16(a1, ones, zl, 0, 0, 0);

            #pragma unroll
            for (int jd = 0; jd < 4; ++jd) {
                const int vrow = (jd * 16 + l15) * 64;
                const bf16x8 b0 = *reinterpret_cast<const bf16x8*>(&Vs[vrow + f0off]);
                const bf16x8 b1 = *reinterpret_cast<const bf16x8*>(&Vs[vrow + f1off]);
                o[jd] = __builtin_amdgcn_mfma_f32_16x16x32_bf16(a0, b0, o[jd], 0, 0, 0);
                o[jd] = __builtin_amdgcn_mfma_f32_16x16x32_bf16(a1, b1, o[jd], 0, 0, 0);
            }
        }

        #pragma unroll
        for (int r = 0; r < 4; ++r) {
            const float inv = 1.f / zl[r];
            const int sq = q0 + wave * 16 + g * 4 + r;
            #pragma unroll
            for (int jd = 0; jd < 4; ++jd)
                ctx[hb + (size_t)sq * DM + jd * 16 + l15] =
                    __float2bfloat16(o[jd][r] * inv);
        }
    }
}

// ---------------------------------------------------------------------------
extern "C" void kernel_launch(void* const* d_in, const int* in_sizes, int n_in,
                              void* d_out, int out_size, void* d_ws, size_t ws_size,
                              hipStream_t stream) {
    const int M = 4 * SEQ;   // 8192

    // size-based input mapping
    int xi = 0, wi[4] = {-1, -1, -1, -1}, bi[4] = {-1, -1, -1, -1};
    int nw = 0, nb = 0;
    for (int i = 0; i < n_in; ++i) {
        if (in_sizes[i] == 4 * SEQ * DM) xi = i;
        else if (in_sizes[i] == DM * DM && nw < 4) wi[nw++] = i;
        else if (in_sizes[i] == DM && nb < 4) bi[nb++] = i;
    }
    if (nw < 4 || nb < 4) {
        const int wOff = n_in - 8;
        for (int j = 0; j < 4; ++j) { wi[j] = wOff + 2 * j; bi[j] = wOff + 2 * j + 1; }
    }
    const void* x  = d_in[xi];
    const void* W[4]  = {d_in[wi[0]], d_in[wi[1]], d_in[wi[2]], d_in[wi[3]]};
    const void* Bs[4] = {d_in[bi[0]], d_in[bi[1]], d_in[bi[2]], d_in[bi[3]]};

    // ws: q | kk | vt | flag (50.33 MB + 4). ctx aliases q. vt (V transposed,
    // written directly by gemm_qkv) occupies the old vv slot.
    const size_t mat = (size_t)M * DM;
    __hip_bfloat16* q   = (__hip_bfloat16*)d_ws;
    __hip_bfloat16* kk  = q + mat;
    __hip_bfloat16* vt  = kk + mat;
    __hip_bfloat16* ctx = q;
    int* flag = (int*)((char*)d_ws + 3 * mat * sizeof(__hip_bfloat16));

    // d_out scratch: xb (16.78 MB) + wb (6.29 MB); both dead before gemm_out.
    __hip_bfloat16* xb  = (__hip_bfloat16*)d_out;
    __hip_bfloat16* wb  = xb + mat;
    __hip_bfloat16* wob = kk;                       // Wo bf16, after attention

    // fused detect + x cast + W0-2 casts (1 launch instead of 3)
    prep_cast<<<dim3(8192 + 3 * 1024), 256, 0, stream>>>(
        x, W[0], W[1], W[2], xb, wb, flag);

    gemm_qkv<<<dim3(M / 128, 24), 256, 0, stream>>>(
        xb, wb, Bs[0], Bs[1], Bs[2], q, kk, vt, flag);

    attn_flash_mfma<<<dim3(1024), 256, 0, stream>>>(q, kk, vt, ctx);

    cast4_kernel<<<dim3(DM * DM / 4 / 256), 256, 0, stream>>>(W[3], wob, flag, DM * DM / 4);

    gemm_out<<<dim3(M / 128, DM / 128), 256, 0, stream>>>(ctx, wob, Bs[3], d_out, flag);
}

// Round 4
// 259.405 us; speedup vs baseline: 1.1007x; 1.0322x over previous
//
#include <hip/hip_runtime.h>
#include <hip/hip_bf16.h>

// MultiHeadSelfAttention  B=4 S=2048 H=16 Dh=64 Dm=1024 (fp32 in/out detected
// at runtime; intermediates bf16).
// Round 13:
//  - attn_flash_mfma: 512-thread / 8-wave blocks on 128-row q-chunks.
//    Each staged 64-key K/V tile (2 gloads) now feeds 8 waves (128 q rows)
//    instead of 4 (64 rows): staging traffic and barrier count per FLOP
//    halved. Per-wave inner compute is byte-identical to R9 (16 q rows,
//    same S^T MFMA, max-free softmax, P round-trip, PV) -> same numerics.
//    Causal: wave skips tiles beyond its rows (wave-uniform), masks the
//    partial tile via qrel = qrow - kbase. LDS 34KB -> 3 blocks/CU
//    (24 waves/CU vs 16). Chunk sizes vary (2..32 tiles), so grid is
//    heavy-first with quartile-mix assignment c=(3-qtr)*4+((j+qtr)&3):
//    each CU-slot's chunk-sum is constant; backfill tail is light blocks.
//  - R3 lesson: launch gap ~3us (not 10-13); launch merging exhausted.
// Keeps: R9 gemm_qkv (m97, 726 TF = its K=1024 ceiling; 8-phase measured
// worse at this shape in R10), prep_cast fusion, workspace layout.

typedef __bf16 bf16x8 __attribute__((ext_vector_type(8)));
typedef __bf16 bf16x4 __attribute__((ext_vector_type(4)));
typedef float  f32x4  __attribute__((ext_vector_type(4)));

#define SEQ 2048
#define NH  16
#define HD  64
#define DM  1024
#define RS  72

static __device__ __forceinline__ void gload_lds16(const __hip_bfloat16* g,
                                                   __hip_bfloat16* l) {
    __builtin_amdgcn_global_load_lds(
        (const __attribute__((address_space(1))) void*)g,
        (__attribute__((address_space(3))) void*)l, 16, 0, 0);
}

// ---------------------------------------------------------------------------
// prep_cast: fused dtype-detect + x->xb + W0..2->wb casts.
// grid: [0,8192) -> x quads; [8192, 8192+3*1024) -> W segments.
// Every block derives the flag locally (2 cached shorts/lane + ballot).
// ---------------------------------------------------------------------------
__global__ __launch_bounds__(256) void prep_cast(
    const void* __restrict__ x,
    const void* __restrict__ w0, const void* __restrict__ w1,
    const void* __restrict__ w2,
    __hip_bfloat16* __restrict__ xb, __hip_bfloat16* __restrict__ wb,
    int* __restrict__ flag)
{
    const unsigned short* xs = (const unsigned short*)x;
    const int lane = threadIdx.x & 63;
    const unsigned e0 = (xs[lane * 4]     >> 7) & 0xFFu;
    const unsigned e1 = (xs[lane * 4 + 2] >> 7) & 0xFFu;
    const unsigned long long b0 = __ballot(e0 >= 0x70u && e0 <= 0x82u);
    const unsigned long long b1 = __ballot(e1 >= 0x70u && e1 <= 0x82u);
    const int cnt = __popcll(b0) + __popcll(b1);
    const bool f32 = (cnt < 64);           // 1 = fp32 data

    const int gid = blockIdx.x;
    if (gid == 0 && threadIdx.x == 0) *flag = f32 ? 1 : 0;

    const void* src;
    __hip_bfloat16* dst;
    int i;
    if (gid < 8192) {
        src = x; dst = xb;
        i = gid * 256 + threadIdx.x;
    } else {
        const int idx = gid - 8192;
        const int w   = idx >> 10;         // 0..2
        const int lb  = idx & 1023;
        src = (w == 0) ? w0 : (w == 1) ? w1 : w2;
        dst = wb + (size_t)w * DM * DM;
        i = lb * 256 + threadIdx.x;
    }

    bf16x4 o;
    if (f32) {
        f32x4 f = ((const f32x4*)src)[i];
        #pragma unroll
        for (int j = 0; j < 4; ++j) o[j] = (__bf16)f[j];
    } else {
        o = ((const bf16x4*)src)[i];
    }
    ((bf16x4*)dst)[i] = o;
}

// cast4 kept for the late Wo cast (dest aliases kk, free only after attn).
__global__ __launch_bounds__(256) void cast4_kernel(
    const void* __restrict__ src, __hip_bfloat16* __restrict__ dst,
    const int* __restrict__ flag, int n4)
{
    const int i = blockIdx.x * 256 + threadIdx.x;
    if (i >= n4) return;
    bf16x4 o;
    if (*flag) {
        f32x4 f = ((const f32x4*)src)[i];
        #pragma unroll
        for (int j = 0; j < 4; ++j) o[j] = (__bf16)f[j];
    } else {
        o = ((const bf16x4*)src)[i];
    }
    ((bf16x4*)dst)[i] = o;
}

// ---------------------------------------------------------------------------
// m97-style GEMM core.
// ---------------------------------------------------------------------------
struct GemmCoord {
    int l15, g, wm, wn, r0, c0;
    int aRead, bRead;
};
static __device__ __forceinline__ GemmCoord gemm_coords() {
    GemmCoord c;
    const int tid = threadIdx.x;
    const int lane = tid & 63, wv = tid >> 6;
    c.l15 = lane & 15; c.g = lane >> 4;
    c.wm = wv >> 1;    c.wn = wv & 1;
    c.r0 = tid >> 2;   c.c0 = tid & 3;
    c.aRead = (c.wm * 64 + c.l15) * 32 + c.g * 8;
    c.bRead = (c.wn * 64 + c.l15) * 32 + c.g * 8;
    return c;
}

#define GEMM_BODY(Aptr, Bptr, m0v, n0v)                                        \
    __shared__ __hip_bfloat16 As[128 * 32];                                    \
    __shared__ __hip_bfloat16 Bs[128 * 32];                                    \
    const GemmCoord cc = gemm_coords();                                        \
    const int wv = threadIdx.x >> 6;                                           \
    const __hip_bfloat16* Ag0 = (Aptr) + (size_t)((m0v) + cc.r0) * DM + cc.c0 * 8;      \
    const __hip_bfloat16* Ag1 = (Aptr) + (size_t)((m0v) + cc.r0 + 64) * DM + cc.c0 * 8; \
    const __hip_bfloat16* Bg0 = (Bptr) + (size_t)((n0v) + cc.r0) * DM + cc.c0 * 8;      \
    const __hip_bfloat16* Bg1 = (Bptr) + (size_t)((n0v) + cc.r0 + 64) * DM + cc.c0 * 8; \
    __hip_bfloat16* AsD0 = As + 512 * wv;                                      \
    __hip_bfloat16* AsD1 = As + 2048 + 512 * wv;                               \
    __hip_bfloat16* BsD0 = Bs + 512 * wv;                                      \
    __hip_bfloat16* BsD1 = Bs + 2048 + 512 * wv;                               \
    f32x4 acc[4][4];                                                           \
    _Pragma("unroll") for (int i = 0; i < 4; ++i)                              \
        _Pragma("unroll") for (int j = 0; j < 4; ++j)                          \
            acc[i][j] = (f32x4){0.f, 0.f, 0.f, 0.f};                           \
    for (int kb = 0; kb < DM; kb += 32) {                                      \
        __syncthreads();                                                       \
        gload_lds16(Ag0 + kb, AsD0);                                           \
        gload_lds16(Ag1 + kb, AsD1);                                           \
        gload_lds16(Bg0 + kb, BsD0);                                           \
        gload_lds16(Bg1 + kb, BsD1);                                           \
        __syncthreads();                                                       \
        bf16x8 af[4], bfr[4];                                                  \
        _Pragma("unroll") for (int i = 0; i < 4; ++i)                          \
            af[i] = *reinterpret_cast<const bf16x8*>(&As[cc.aRead + i * 512]); \
        _Pragma("unroll") for (int j = 0; j < 4; ++j)                          \
            bfr[j] = *reinterpret_cast<const bf16x8*>(&Bs[cc.bRead + j * 512]);\
        _Pragma("unroll") for (int i = 0; i < 4; ++i)                          \
            _Pragma("unroll") for (int j = 0; j < 4; ++j)                      \
                acc[i][j] = __builtin_amdgcn_mfma_f32_16x16x32_bf16(           \
                    af[i], bfr[j], acc[i][j], 0, 0, 0);                        \
    }

// Fused QKV (R9). widx 0/1 -> q/kk normal layout; widx 2 -> V stored
// transposed into vt[(b*16+h)*64+d][t] via 16x 8B stores.
__global__ __launch_bounds__(256) void gemm_qkv(
    const __hip_bfloat16* __restrict__ A,
    const __hip_bfloat16* __restrict__ Wb,
    const void* bq, const void* bk, const void* bv,
    __hip_bfloat16* q, __hip_bfloat16* kk, __hip_bfloat16* vt,
    const int* __restrict__ dflag)
{
    const int widx = blockIdx.y >> 3;
    const int m0 = blockIdx.x * 128;
    const int n0 = (blockIdx.y & 7) * 128;
    const __hip_bfloat16* B = Wb + (size_t)widx * DM * DM;
    const void* bias = (widx == 0) ? bq : (widx == 1) ? bk : bv;
    const bool f32 = (*dflag != 0);

    GEMM_BODY(A, B, m0, n0)

    if (widx == 2) {
        #pragma unroll
        for (int j = 0; j < 4; ++j) {
            const int col = n0 + cc.wn * 64 + j * 16 + cc.l15;
            const float bvv = f32 ? ((const float*)bias)[col]
                                  : __bfloat162float(((const __hip_bfloat16*)bias)[col]);
            #pragma unroll
            for (int i = 0; i < 4; ++i) {
                const int row0 = m0 + cc.wm * 64 + i * 16 + cc.g * 4; // r=0 row
                const int bb = row0 >> 11;
                const int t  = row0 & 2047;
                bf16x4 pv;
                #pragma unroll
                for (int r = 0; r < 4; ++r)
                    pv[r] = (__bf16)(acc[i][j][r] + bvv);
                *reinterpret_cast<bf16x4*>(
                    vt + (size_t)(bb * 1024 + col) * SEQ + t) = pv;
            }
        }
    } else {
        __hip_bfloat16* out = (widx == 0) ? q : kk;
        #pragma unroll
        for (int j = 0; j < 4; ++j) {
            const int col = n0 + cc.wn * 64 + j * 16 + cc.l15;
            const float bvv = f32 ? ((const float*)bias)[col]
                                  : __bfloat162float(((const __hip_bfloat16*)bias)[col]);
            #pragma unroll
            for (int i = 0; i < 4; ++i) {
                #pragma unroll
                for (int r = 0; r < 4; ++r) {
                    const int row = m0 + cc.wm * 64 + i * 16 + cc.g * 4 + r;
                    out[(size_t)row * DM + col] = __float2bfloat16(acc[i][j][r] + bvv);
                }
            }
        }
    }
}

__global__ __launch_bounds__(256) void gemm_out(
    const __hip_bfloat16* __restrict__ A,
    const __hip_bfloat16* __restrict__ B,
    const void* bias, void* __restrict__ outv,
    const int* __restrict__ dflag)
{
    const int m0 = blockIdx.x * 128;
    const int n0 = blockIdx.y * 128;
    const bool f32 = (*dflag != 0);

    GEMM_BODY(A, B, m0, n0)

    #pragma unroll
    for (int j = 0; j < 4; ++j) {
        const int col = n0 + cc.wn * 64 + j * 16 + cc.l15;
        const float bvv = f32 ? ((const float*)bias)[col]
                              : __bfloat162float(((const __hip_bfloat16*)bias)[col]);
        #pragma unroll
        for (int i = 0; i < 4; ++i) {
            #pragma unroll
            for (int r = 0; r < 4; ++r) {
                const int row = m0 + cc.wm * 64 + i * 16 + cc.g * 4 + r;
                const float val = acc[i][j][r] + bvv;
                if (f32) ((float*)outv)[(size_t)row * DM + col] = val;
                else ((__hip_bfloat16*)outv)[(size_t)row * DM + col] = __float2bfloat16(val);
            }
        }
    }
}

// ---------------------------------------------------------------------------
// Flash attention (S^T orientation), 8-wave / 128-row chunks.
// Per-wave compute identical to R9. Staging: one 64-key tile (K 8KB + V 8KB,
// 2 gloads over 512 threads) serves all 8 waves. Wave w owns rows
// base + w*16 + l15. Tiles fully beyond a wave's rows are skipped
// (wave-uniform); the partial tile masks via qrel = qrow - kbase.
// Grid: 1024 blocks; c = (3-qtr)*4 + ((j+qtr)&3) -> heavy chunks first,
// constant expected chunk-sum per CU slot.
// ---------------------------------------------------------------------------
__global__ __launch_bounds__(512) void attn_flash_mfma(
    const __hip_bfloat16* __restrict__ q,
    const __hip_bfloat16* __restrict__ k,
    const __hip_bfloat16* __restrict__ vt,   // [b][h][d][t]
    __hip_bfloat16* __restrict__ ctx)
{
    __shared__ __hip_bfloat16 Ks[64 * HD];        // 8KB swizzled K tile
    __shared__ __hip_bfloat16 Vs[HD * 64];        // 8KB swizzled VT tile
    __shared__ __hip_bfloat16 P[8][16 * RS];      // per-wave P (18KB)

    const int tid  = threadIdx.x;
    const int lane = tid & 63;
    const int wv   = tid >> 6;       // 0..7
    const int g    = lane >> 4;
    const int l15  = lane & 15;
    const int l7   = l15 & 7;

    // heavy-first, quartile-mixed chunk assignment
    const int bid  = blockIdx.x;     // 0..1023
    const int pos  = bid & 255;
    const int qtr  = bid >> 8;       // 0..3
    const int h64  = pos & 63;       // b*16+h
    const int jj   = pos >> 6;       // 0..3
    const int c    = (3 - qtr) * 4 + ((jj + qtr) & 3);   // 0..15, heavy first
    const int b    = h64 >> 4;
    const int h    = h64 & 15;
    const int base = c * 128;
    const int nt   = 2 * c + 2;      // tiles for this chunk

    const size_t hb = (size_t)b * SEQ * DM + (size_t)h * HD;
    const __hip_bfloat16* vth = vt + (size_t)(b * NH + h) * HD * SEQ;
    __hip_bfloat16* Pw = P[wv];

    // staging coords (512 threads cover one 8KB tile per gload)
    const int kr0 = tid >> 3;
    const int ks0 = ((tid & 7) ^ (kr0 & 7)) * 8;
    __hip_bfloat16* KsD = Ks + wv * 512;
    __hip_bfloat16* VsD = Vs + wv * 512;

    const int f0off = ((g ^ l7)) * 8;
    const int f1off = (((4 + g) ^ l7)) * 8;

    bf16x8 ones;
    #pragma unroll
    for (int j = 0; j < 8; ++j) ones[j] = (__bf16)1.0f;

    const int rmin = base + wv * 16;
    const int qrow = rmin + l15;
    const __hip_bfloat16* qp_ = q + hb + (size_t)qrow * DM + g * 8;
    bf16x8 qf0 = *reinterpret_cast<const bf16x8*>(qp_);
    bf16x8 qf1 = *reinterpret_cast<const bf16x8*>(qp_ + 32);
    #pragma unroll
    for (int j = 0; j < 8; ++j) {
        qf0[j] = (__bf16)((float)qf0[j] * 0.125f);   // 1/sqrt(64)
        qf1[j] = (__bf16)((float)qf1[j] * 0.125f);
    }

    f32x4 o[4];
    #pragma unroll
    for (int j = 0; j < 4; ++j) o[j] = (f32x4){0.f, 0.f, 0.f, 0.f};
    f32x4 zl = (f32x4){0.f, 0.f, 0.f, 0.f};   // row sums of P

    for (int t = 0; t < nt; ++t) {
        const int kbase = t * 64;

        __syncthreads();
        gload_lds16(k + hb + (size_t)(kbase + kr0) * DM + ks0, KsD);
        gload_lds16(vth + (size_t)kr0 * SEQ + kbase + ks0, VsD);
        __syncthreads();

        if (kbase <= rmin + 15) {      // wave-uniform: tile touches our rows
            // ---- S^T = K (Q/8)^T ---------------------------------------
            f32x4 s[4];
            #pragma unroll
            for (int j = 0; j < 4; ++j) {
                const int krow = (j * 16 + l15) * 64;
                bf16x8 kf0 = *reinterpret_cast<const bf16x8*>(&Ks[krow + f0off]);
                bf16x8 kf1 = *reinterpret_cast<const bf16x8*>(&Ks[krow + f1off]);
                f32x4 z = (f32x4){0.f, 0.f, 0.f, 0.f};
                z = __builtin_amdgcn_mfma_f32_16x16x32_bf16(kf0, qf0, z, 0, 0, 0);
                z = __builtin_amdgcn_mfma_f32_16x16x32_bf16(kf1, qf1, z, 0, 0, 0);
                s[j] = z;   // s[j][r]: key = kbase + j*16 + g*4 + r, query = qrow
            }

            // ---- causal mask (partial tile only; wave-uniform cond) -----
            if (kbase + 63 > rmin) {
                const int qrel = qrow - kbase;
                #pragma unroll
                for (int j = 0; j < 4; ++j) {
                    #pragma unroll
                    for (int r = 0; r < 4; ++r) {
                        const int key = j * 16 + g * 4 + r;
                        if (key > qrel) s[j][r] = -1e30f;
                    }
                }
            }

            // ---- max-free softmax: p = exp(s) ---------------------------
            #pragma unroll
            for (int j = 0; j < 4; ++j)
                #pragma unroll
                for (int r = 0; r < 4; ++r)
                    s[j][r] = __expf(s[j][r]);

            // ---- P: S^T C-layout -> A-layout, one b64 per j -------------
            #pragma unroll
            for (int j = 0; j < 4; ++j) {
                bf16x4 pv;
                #pragma unroll
                for (int r = 0; r < 4; ++r) pv[r] = (__bf16)s[j][r];
                *reinterpret_cast<bf16x4*>(&Pw[l15 * RS + j * 16 + g * 4]) = pv;
            }

            const bf16x8 a0 = *reinterpret_cast<const bf16x8*>(&Pw[l15 * RS + g * 8]);
            const bf16x8 a1 = *reinterpret_cast<const bf16x8*>(&Pw[l15 * RS + 32 + g * 8]);

            // ---- l += P @ ones ------------------------------------------
            zl = __builtin_amdgcn_mfma_f32_16x16x32_bf16(a0, ones, zl, 0, 0, 0);
            zl = __builtin_amdgcn_mfma_f32_16x16x32_bf16(a1, ones, zl, 0, 0, 0);

            // ---- O += P V  (VT frags from LDS) --------------------------
            #pragma unroll
            for (int jd = 0; jd < 4; ++jd) {
                const int vrow = (jd * 16 + l15) * 64;
                const bf16x8 b0 = *reinterpret_cast<const bf16x8*>(&Vs[vrow + f0off]);
                const bf16x8 b1 = *reinterpret_cast<const bf16x8*>(&Vs[vrow + f1off]);
                o[jd] = __builtin_amdgcn_mfma_f32_16x16x32_bf16(a0, b0, o[jd], 0, 0, 0);
                o[jd] = __builtin_amdgcn_mfma_f32_16x16x32_bf16(a1, b1, o[jd], 0, 0, 0);
            }
        }
    }

    // ---- epilogue: ctx = O / l ------------------------------------------
    #pragma unroll
    for (int r = 0; r < 4; ++r) {
        const float inv = 1.f / zl[r];
        const int sq = rmin + g * 4 + r;
        #pragma unroll
        for (int jd = 0; jd < 4; ++jd)
            ctx[hb + (size_t)sq * DM + jd * 16 + l15] =
                __float2bfloat16(o[jd][r] * inv);
    }
}

// ---------------------------------------------------------------------------
extern "C" void kernel_launch(void* const* d_in, const int* in_sizes, int n_in,
                              void* d_out, int out_size, void* d_ws, size_t ws_size,
                              hipStream_t stream) {
    const int M = 4 * SEQ;   // 8192

    // size-based input mapping
    int xi = 0, wi[4] = {-1, -1, -1, -1}, bi[4] = {-1, -1, -1, -1};
    int nw = 0, nb = 0;
    for (int i = 0; i < n_in; ++i) {
        if (in_sizes[i] == 4 * SEQ * DM) xi = i;
        else if (in_sizes[i] == DM * DM && nw < 4) wi[nw++] = i;
        else if (in_sizes[i] == DM && nb < 4) bi[nb++] = i;
    }
    if (nw < 4 || nb < 4) {
        const int wOff = n_in - 8;
        for (int j = 0; j < 4; ++j) { wi[j] = wOff + 2 * j; bi[j] = wOff + 2 * j + 1; }
    }
    const void* x  = d_in[xi];
    const void* W[4]  = {d_in[wi[0]], d_in[wi[1]], d_in[wi[2]], d_in[wi[3]]};
    const void* Bs[4] = {d_in[bi[0]], d_in[bi[1]], d_in[bi[2]], d_in[bi[3]]};

    // ws: q | kk | vt | flag (50.33 MB + 4). ctx aliases q. vt (V transposed,
    // written directly by gemm_qkv) occupies the old vv slot.
    const size_t mat = (size_t)M * DM;
    __hip_bfloat16* q   = (__hip_bfloat16*)d_ws;
    __hip_bfloat16* kk  = q + mat;
    __hip_bfloat16* vt  = kk + mat;
    __hip_bfloat16* ctx = q;
    int* flag = (int*)((char*)d_ws + 3 * mat * sizeof(__hip_bfloat16));

    // d_out scratch: xb (16.78 MB) + wb (6.29 MB); both dead before gemm_out.
    __hip_bfloat16* xb  = (__hip_bfloat16*)d_out;
    __hip_bfloat16* wb  = xb + mat;
    __hip_bfloat16* wob = kk;                       // Wo bf16, after attention

    // fused detect + x cast + W0-2 casts
    prep_cast<<<dim3(8192 + 3 * 1024), 256, 0, stream>>>(
        x, W[0], W[1], W[2], xb, wb, flag);

    gemm_qkv<<<dim3(M / 128, 24), 256, 0, stream>>>(
        xb, wb, Bs[0], Bs[1], Bs[2], q, kk, vt, flag);

    attn_flash_mfma<<<dim3(1024), 512, 0, stream>>>(q, kk, vt, ctx);

    cast4_kernel<<<dim3(DM * DM / 4 / 256), 256, 0, stream>>>(W[3], wob, flag, DM * DM / 4);

    gemm_out<<<dim3(M / 128, DM / 128), 256, 0, stream>>>(ctx, wob, Bs[3], d_out, flag);
}